// Round 6
// baseline (183.000 us; speedup 1.0000x reference)
//
#include <hip/hip_runtime.h>
#include <hip/hip_bf16.h>
#include <cstdint>
#include <cstddef>

// ---------------------------------------------------------------------------
// MAT_31997506355868 round 15.
// R14 + phase-count halving at constant bytes (R13 showed per-phase fixed
// cost): attn j-chunks 64->128 (16->8 phases; K 16KB + V 16KB, 2-buf 64KB
// LDS, 2 blk/CU), colsum i-chunks 64->128 (8->4 phases, 2-buf 32KB, 4
// blk/CU).  Schedule per phase: vmcnt(0) [stage(ch) had a full compute
// phase of cover] -> barrier -> stage(ch+1) -> compute.  qkv/convert = R14.
// ---------------------------------------------------------------------------

typedef short short8 __attribute__((ext_vector_type(8)));
typedef short short4v __attribute__((ext_vector_type(4)));
typedef float f32x4 __attribute__((ext_vector_type(4)));

#define MFMA32(a, b, c) __builtin_amdgcn_mfma_f32_16x16x32_bf16(a, b, c, 0, 0, 0)
#define MFMA16x16(a, b, c) __builtin_amdgcn_mfma_f32_16x16x16bf16_1k(a, b, c, 0, 0, 0)
// Q pre-scale: (1/32) * log2(e)  -> scores arrive in log2 domain
#define QSCALE 0.045084220027780106f

__device__ __forceinline__ short f2bf(float f) {
  union { float f; uint32_t u; } x; x.f = f;
  uint32_t u = x.u + 0x7fffu + ((x.u >> 16) & 1u);  // RNE
  return (short)(u >> 16);
}

// pack two fp32 -> two bf16 (truncate) in one v_perm_b32
__device__ __forceinline__ uint32_t pk_bf16_trunc(float lo, float hi) {
  return __builtin_amdgcn_perm(__float_as_uint(hi), __float_as_uint(lo),
                               0x07060302u);
}

// async global->LDS; LDS dest = wave-uniform base + lane*size
#define GLDS16(gp, lp)                                                        \
  __builtin_amdgcn_global_load_lds(                                           \
      (const __attribute__((address_space(1))) void*)(gp),                    \
      (__attribute__((address_space(3))) void*)(lp), 16, 0, 0)
#define GLDS4(gp, lp)                                                         \
  __builtin_amdgcn_global_load_lds(                                           \
      (const __attribute__((address_space(1))) void*)(gp),                    \
      (__attribute__((address_space(3))) void*)(lp), 4, 0, 0)

// ---- fp32 -> bf16 convert + zero out2 -------------------------------------
__global__ __launch_bounds__(256) void convert_kernel(
    const float* __restrict__ x, const float* __restrict__ wq,
    const float* __restrict__ wk, const float* __restrict__ wv,
    short* __restrict__ xb, short* __restrict__ wb,
    float* __restrict__ out2) {
  if (blockIdx.x >= 7168) {  // zero out2 (64K floats) for colsum atomics
    const int idx = (blockIdx.x - 7168) * 256 + threadIdx.x;
    *(f32x4*)(out2 + (size_t)idx * 4) = (f32x4){0.f, 0.f, 0.f, 0.f};
    return;
  }
  const long XN = 4L * 1024 * 1024, WN = 1024L * 1024;
  long e = (long)(blockIdx.x * blockDim.x + threadIdx.x) * 4;
  const float* src; short* dst;
  if (e < XN)               { src = x  + e;                dst = xb + e; }
  else if (e < XN + WN)     { src = wq + (e - XN);         dst = wb + (e - XN); }
  else if (e < XN + 2 * WN) { src = wk + (e - XN - WN);    dst = wb + (e - XN); }
  else                      { src = wv + (e - XN - 2*WN);  dst = wb + (e - XN); }
  f32x4 v = *(const f32x4*)src;
  short4v o;
  o[0] = f2bf(v[0]); o[1] = f2bf(v[1]); o[2] = f2bf(v[2]); o[3] = f2bf(v[3]);
  *(short4v*)dst = o;
}

// ---- QKV projection: m97 BK=64 + both-sides XOR swizzle.  Q scaled --------
// by (1/32)*log2e so attention uses 2^z.  z==2 (V): writes V^T frag-major.
__global__ __launch_bounds__(256, 3) void qkv_gemm(
    const short* __restrict__ xb, const short* __restrict__ wb,
    const float* __restrict__ bq, const float* __restrict__ bk,
    const float* __restrict__ bv, short* __restrict__ qb,
    short* __restrict__ kb, short* __restrict__ vtp) {
  __shared__ short As[128 * 64];   // 16 KB
  __shared__ short Bs[128 * 64];   // 16 KB
  const int tid = threadIdx.x;
  const int lane = tid & 63;
  const int lm = lane & 15, quad = lane >> 4;
  const int wave = tid >> 6, wy = wave >> 1, wx = wave & 1;
  // flat = bx + 8*by; XCD = flat & 7 (x-fastest round-robin)
  const int f = blockIdx.x + (blockIdx.y << 3);
  const int r8 = f & 7, s = f >> 3;
  const int m0 = (((r8 >> 1) << 3) + (s & 7)) * 128;
  const int n0 = (((r8 & 1) << 2) + (s >> 3)) * 128;
  const int z = blockIdx.z;
  const short* w = wb + (size_t)z * (1024 * 1024);
  const float* bias = (z == 0) ? bq : (z == 1) ? bk : bv;
  const float scl = (z == 0) ? QSCALE : 1.0f;

  // staging: thread t loads row (t>>3)+32q, source chunk (t&7)^(row&7);
  // GLDS dest linear (row-major [128][64]); (row&7) invariant in q.
  const int srow = tid >> 3;
  const int schk = (tid & 7) ^ (srow & 7);
  const short* gA = xb + (size_t)(m0 + srow) * 1024 + schk * 8;
  const short* gB = w  + (size_t)(n0 + srow) * 1024 + schk * 8;
  short* lA = As + tid * 8;
  short* lB = Bs + tid * 8;

  f32x4 acc[4][4];
#pragma unroll
  for (int i = 0; i < 4; i++)
#pragma unroll
    for (int j = 0; j < 4; j++) acc[i][j] = (f32x4){0.f, 0.f, 0.f, 0.f};

  for (int k0 = 0; k0 < 1024; k0 += 64) {
#pragma unroll
    for (int q = 0; q < 4; q++) {
      GLDS16(gA + k0 + q * 32 * 1024, lA + q * 2048);
      GLDS16(gB + k0 + q * 32 * 1024, lB + q * 2048);
    }
    __syncthreads();
#pragma unroll
    for (int ks = 0; ks < 2; ks++) {
      const int ck = (((ks << 2) + quad) ^ (lm & 7)) * 8;  // swizzled chunk
      short8 a[4], b[4];
#pragma unroll
      for (int t = 0; t < 4; t++) {
        a[t] = *(const short8*)(As + (wy * 64 + t * 16 + lm) * 64 + ck);
        b[t] = *(const short8*)(Bs + (wx * 64 + t * 16 + lm) * 64 + ck);
      }
#pragma unroll
      for (int mt = 0; mt < 4; mt++)
#pragma unroll
        for (int nt = 0; nt < 4; nt++)
          acc[mt][nt] = MFMA32(a[mt], b[nt], acc[mt][nt]);
    }
    __syncthreads();
  }
  if (z == 2) {
    // V: write transposed frag-major directly
#pragma unroll
    for (int nt = 0; nt < 4; nt++) {
      const int n = n0 + wx * 64 + nt * 16 + lm;
      const float bn = bias[n];
      const size_t nbase = (size_t)((n >> 4) & 3) * 16384 +
                           (size_t)((((n >> 8) & 3) * 16 + (n & 15)) * 4 +
                                    ((n >> 6) & 3));
#pragma unroll
      for (int mt = 0; mt < 4; mt++) {
#pragma unroll
        for (int r = 0; r < 4; r++) {
          const int m = m0 + wy * 64 + mt * 16 + quad * 4 + r;
          vtp[(size_t)(m >> 6) * 65536 + nbase + (size_t)(m & 63) * 256] =
              f2bf(acc[mt][nt][r] + bn);
        }
      }
    }
  } else {
    short* out = (z == 0) ? qb : kb;
#pragma unroll
    for (int nt = 0; nt < 4; nt++) {
      const int n = n0 + wx * 64 + nt * 16 + lm;
      const float bn = bias[n];
#pragma unroll
      for (int mt = 0; mt < 4; mt++) {
        const int mb = m0 + wy * 64 + mt * 16 + quad * 4;
#pragma unroll
        for (int r = 0; r < 4; r++)
          out[(size_t)(mb + r) * 1024 + n] = f2bf((acc[mt][nt][r] + bn) * scl);
      }
    }
  }
}

// ---- FLASH attention: 2 i-tiles/wave, 128-j chunks (8 phases), 2-buf ------
// grid 512 = 64 heads x 8 blocks; head-grouped XCD swizzle.  Per phase:
// vmcnt(0) [stage(ch) had a full compute phase of cover] -> barrier ->
// stage(ch+1) -> compute.  LDS 64 KB/block, 2 blocks/CU.
__global__ __launch_bounds__(256, 2) void attn_kernel(
    const short* __restrict__ qb, const short* __restrict__ kb,
    const short* __restrict__ vtp, const float* __restrict__ x,
    const float* __restrict__ gamma, const float* __restrict__ beta,
    float* __restrict__ out1, float* __restrict__ rvW) {
  __shared__ short Ks[2][128 * 64];   // 2 x 16 KB
  __shared__ short Vs[2][8192];       // 2 x 16 KB

  const int tid = threadIdx.x;
  const int lane = tid & 63, wave = tid >> 6;
  const int lm = lane & 15, quad = lane >> 4;
  const int bid = blockIdx.x;
  const int h = ((bid >> 6) << 3) + (bid & 7);   // bid ≡ h (mod 8)
  const int bb = (bid >> 3) & 7;
  const short* Qh = qb + (size_t)h * 65536;
  const short* Kh = kb + (size_t)h * 65536;
  const short* Vp = vtp + (size_t)h * 65536;
  const int i0 = bb * 128 + wave * 32;   // tiles at i0 and i0+16

  const short8 qA0 = *(const short8*)(Qh + (size_t)(i0 + lm) * 64 + quad * 8);
  const short8 qA1 = *(const short8*)(Qh + (size_t)(i0 + lm) * 64 + 32 + quad * 8);
  const short8 qB0 = *(const short8*)(Qh + (size_t)(i0 + 16 + lm) * 64 + quad * 8);
  const short8 qB1 = *(const short8*)(Qh + (size_t)(i0 + 16 + lm) * 64 + 32 + quad * 8);

  // K staging: 4 parts cover 128 rows; XOR-swizzled source, linear LDS dest
  const short* gKp[4];
  int lKp[4];
#pragma unroll
  for (int p = 0; p < 4; p++) {
    const int fl = tid + 256 * p;
    gKp[p] = Kh + (size_t)(fl >> 3) * 64 + ((fl & 7) ^ ((fl >> 3) & 7)) * 8;
    lKp[p] = fl * 8;
  }
  // V staging: two 64-j sub-blocks per chunk (original frag-major map)
  const int c0 = tid, c1 = tid + 256;
  const short* gV0 = Vp + (c0 >> 7) * 16384 + ((c0 >> 5) & 3) * 256 + (c0 & 31) * 8;
  const short* gV1 = Vp + (c1 >> 7) * 16384 + ((c1 >> 5) & 3) * 256 + (c1 & 31) * 8;

#define ATTN_STAGE(c, buf)                                                    \
  do {                                                                        \
    _Pragma("unroll")                                                         \
    for (int p_ = 0; p_ < 4; p_++)                                            \
      GLDS16(gKp[p_] + (c) * 8192, &Ks[buf][0] + lKp[p_]);                    \
    _Pragma("unroll")                                                         \
    for (int p_ = 0; p_ < 2; p_++) {                                          \
      GLDS16(gV0 + ((c) * 2 + p_) * 1024, &Vs[buf][p_ * 4096] + tid * 8);     \
      GLDS16(gV1 + ((c) * 2 + p_) * 1024,                                     \
             &Vs[buf][p_ * 4096] + (tid + 256) * 8);                          \
    }                                                                         \
  } while (0)

  f32x4 accA[4], accB[4];
#pragma unroll
  for (int t = 0; t < 4; t++) {
    accA[t] = (f32x4){0.f, 0.f, 0.f, 0.f};
    accB[t] = (f32x4){0.f, 0.f, 0.f, 0.f};
  }
  float dsA[4] = {0.f, 0.f, 0.f, 0.f};
  float dsB[4] = {0.f, 0.f, 0.f, 0.f};

  const int swz0 = (quad ^ (lm & 7)) * 8;
  const int swz1 = ((quad + 4) ^ (lm & 7)) * 8;

  ATTN_STAGE(0, 0);

  for (int ch = 0; ch < 8; ch++) {
    const int b = ch & 1;
    asm volatile("s_waitcnt vmcnt(0)" ::: "memory");
    __builtin_amdgcn_s_barrier();
    // buf b^1 was last read by compute(ch-1), published by this barrier
    if (ch < 7) ATTN_STAGE(ch + 1, b ^ 1);
    __builtin_amdgcn_s_setprio(1);
#pragma unroll
    for (int jj = 0; jj < 8; jj++) {
      const short* krow = &Ks[b][(jj * 16 + lm) * 64];
      const short8 kf0 = *(const short8*)(krow + swz0);
      const short8 kf1 = *(const short8*)(krow + swz1);
      f32x4 zA = {0.f, 0.f, 0.f, 0.f};
      zA = MFMA32(kf0, qA0, zA);
      zA = MFMA32(kf1, qA1, zA);
      f32x4 zB = {0.f, 0.f, 0.f, 0.f};
      zB = MFMA32(kf0, qB0, zB);
      zB = MFMA32(kf1, qB1, zB);
      float pA[4], pB[4];
#pragma unroll
      for (int r = 0; r < 4; r++) {
        pA[r] = __builtin_amdgcn_exp2f(fmaxf(zA[r], 0.f));  // unnormalized
        dsA[r] += pA[r];
        pB[r] = __builtin_amdgcn_exp2f(fmaxf(zB[r], 0.f));
        dsB[r] += pB[r];
      }
      union { uint32_t u[2]; short4v s; } puA, puB;
      puA.u[0] = pk_bf16_trunc(pA[0], pA[1]);
      puA.u[1] = pk_bf16_trunc(pA[2], pA[3]);
      puB.u[0] = pk_bf16_trunc(pB[0], pB[1]);
      puB.u[1] = pk_bf16_trunc(pB[2], pB[3]);
      const short* vbase = &Vs[b][(jj >> 2) * 4096 + (jj & 3) * 256 + lane * 4];
#pragma unroll
      for (int dt = 0; dt < 4; dt++) {
        const short4v vtf = *(const short4v*)(vbase + dt * 1024);
        accA[dt] = MFMA16x16(vtf, puA.s, accA[dt]);
        accB[dt] = MFMA16x16(vtf, puB.s, accB[dt]);
      }
    }
    __builtin_amdgcn_s_setprio(0);
  }

  float tA = (dsA[0] + dsA[1]) + (dsA[2] + dsA[3]);
  tA += __shfl_xor(tA, 16);
  tA += __shfl_xor(tA, 32);
  float tB = (dsB[0] + dsB[1]) + (dsB[2] + dsB[3]);
  tB += __shfl_xor(tB, 16);
  tB += __shfl_xor(tB, 32);
  const float rvA = 1.f / tA;
  const float rvB = 1.f / tB;
  if (lane < 16) {
    rvW[h * 1024 + i0 + lm] = rvA;
    rvW[h * 1024 + i0 + 16 + lm] = rvB;
  }

  // ---- LN epilogue (R4-verified 2-tile): n = lm*64 + dt*16 + quad*4+r -----
  const int mA = h * 64 + bb * 8 + wave * 2;  // tile A row; tile B = mA+1
  const int nb = lm * 64 + quad * 4;
#pragma unroll
  for (int tile = 0; tile < 2; tile++) {
    const int m = mA + tile;
    const f32x4* accT = tile ? accB : accA;
    const float rv = tile ? rvB : rvA;
    const float* xr = x + (size_t)m * 1024;
    float hv[4][4], s1 = 0.f, s2 = 0.f;
#pragma unroll
    for (int dt = 0; dt < 4; dt++) {
      f32x4 xv = *(const f32x4*)(xr + nb + dt * 16);
#pragma unroll
      for (int r = 0; r < 4; r++) {
        const float v = xv[r] + accT[dt][r] * rv;
        hv[dt][r] = v; s1 += v; s2 += v * v;
      }
    }
#pragma unroll
    for (int mk = 1; mk < 64; mk <<= 1) {
      s1 += __shfl_xor(s1, mk);
      s2 += __shfl_xor(s2, mk);
    }
    const float mu = s1 * (1.f / 1024.f);
    const float var = s2 * (1.f / 1024.f) - mu * mu;
    const float rstd = rsqrtf(var + 1e-5f);
    float* orow = out1 + (size_t)m * 1024;
#pragma unroll
    for (int dt = 0; dt < 4; dt++) {
      f32x4 gv = *(const f32x4*)(gamma + nb + dt * 16);
      f32x4 bv2 = *(const f32x4*)(beta + nb + dt * 16);
      f32x4 ov;
#pragma unroll
      for (int r = 0; r < 4; r++)
        ov[r] = (hv[dt][r] - mu) * rstd * gv[r] + bv2[r];
      *(f32x4*)(orow + nb + dt * 16) = ov;
    }
  }
}

// ---- colsum: 2 j-tiles/wave, i-halves, 128-i chunks (4 phases), 2-buf -----
// grid 1024 = 64 heads x 2 i-halves x 8 j-blocks; 4 blk/CU; atomicAdd merge.
__global__ __launch_bounds__(256, 4) void colsum_kernel(
    const short* __restrict__ qb, const short* __restrict__ kb,
    const float* __restrict__ rvW, float* __restrict__ out2) {
  __shared__ short Qs[2][128 * 64];  // 2 x 16 KB
  __shared__ float rvS[2][128];

  const int tid = threadIdx.x;
  const int lane = tid & 63, wave = tid >> 6;
  const int lm = lane & 15, quad = lane >> 4;
  const int bid = blockIdx.x;                    // [hhh][i][jjj][lll]
  const int h = ((bid >> 7) << 3) + (bid & 7);   // bid ≡ h (mod 8)
  const int jb = (bid >> 3) & 7;
  const int ih = (bid >> 6) & 1;
  const int cb = ih * 4;                         // chunk base (i = cb*128)
  const int j0 = jb * 128 + wave * 32;
  const short* Qh = qb + (size_t)h * 65536;
  const short* Kh = kb + (size_t)h * 65536;
  const float* rvh = rvW + h * 1024;

  const short* krA = Kh + (size_t)(j0 + lm) * 64 + quad * 8;
  const short8 kA0 = *(const short8*)krA;
  const short8 kA1 = *(const short8*)(krA + 32);
  const short* krB = Kh + (size_t)(j0 + 16 + lm) * 64 + quad * 8;
  const short8 kB0 = *(const short8*)krB;
  const short8 kB1 = *(const short8*)(krB + 32);

  const short* gQp[4];
  int lQp[4];
#pragma unroll
  for (int p = 0; p < 4; p++) {
    const int fl = tid + 256 * p;
    gQp[p] = Qh + (size_t)(fl >> 3) * 64 + ((fl & 7) ^ ((fl >> 3) & 7)) * 8;
    lQp[p] = fl * 8;
  }

#define CS_STAGE(c, buf)                                                      \
  do {                                                                        \
    _Pragma("unroll")                                                         \
    for (int p_ = 0; p_ < 4; p_++)                                            \
      GLDS16(gQp[p_] + (c) * 8192, &Qs[buf][0] + lQp[p_]);                    \
    if (wave == 0) {                                                          \
      GLDS4(rvh + (c) * 128 + lane, &rvS[buf][0]);                            \
      GLDS4(rvh + (c) * 128 + 64 + lane, &rvS[buf][64]);                      \
    }                                                                         \
  } while (0)

  const int swz0 = (quad ^ (lm & 7)) * 8;
  const int swz1 = ((quad + 4) ^ (lm & 7)) * 8;

  f32x4 csA = {0.f, 0.f, 0.f, 0.f};
  f32x4 csB = {0.f, 0.f, 0.f, 0.f};

  CS_STAGE(cb, 0);

  for (int ch = 0; ch < 4; ch++) {
    const int b = ch & 1;
    asm volatile("s_waitcnt vmcnt(0)" ::: "memory");
    __builtin_amdgcn_s_barrier();
    if (ch < 3) CS_STAGE(cb + ch + 1, b ^ 1);
    __builtin_amdgcn_s_setprio(1);
#pragma unroll
    for (int ii = 0; ii < 8; ii++) {
      const short* qrow = &Qs[b][(ii * 16 + lm) * 64];
      const short8 qf0 = *(const short8*)(qrow + swz0);
      const short8 qf1 = *(const short8*)(qrow + swz1);
      f32x4 zA = {0.f, 0.f, 0.f, 0.f};
      zA = MFMA32(kA0, qf0, zA);
      zA = MFMA32(kA1, qf1, zA);
      f32x4 zB = {0.f, 0.f, 0.f, 0.f};
      zB = MFMA32(kB0, qf0, zB);
      zB = MFMA32(kB1, qf1, zB);
      const float rvv = rvS[b][ii * 16 + lm];
#pragma unroll
      for (int r = 0; r < 4; r++) {
        csA[r] += __builtin_amdgcn_exp2f(fmaxf(zA[r], 0.f)) * rvv;
        csB[r] += __builtin_amdgcn_exp2f(fmaxf(zB[r], 0.f)) * rvv;
      }
    }
    __builtin_amdgcn_s_setprio(0);
  }

  // reduce over the 16 i-lanes within each quad, then merge i-halves
#pragma unroll
  for (int mk = 1; mk < 16; mk <<= 1)
#pragma unroll
    for (int r = 0; r < 4; r++) {
      csA[r] += __shfl_xor(csA[r], mk);
      csB[r] += __shfl_xor(csB[r], mk);
    }
  if (lm == 0) {
    float* pA = out2 + h * 1024 + j0 + quad * 4;
    float* pB = pA + 16;
#pragma unroll
    for (int r = 0; r < 4; r++) {
      atomicAdd(pA + r, csA[r]);
      atomicAdd(pB + r, csB[r]);
    }
  }
}

extern "C" void kernel_launch(void* const* d_in, const int* in_sizes, int n_in,
                              void* d_out, int out_size, void* d_ws, size_t ws_size,
                              hipStream_t stream) {
  const float* x  = (const float*)d_in[0];
  const float* Wq = (const float*)d_in[1];
  const float* bq = (const float*)d_in[2];
  const float* Wk = (const float*)d_in[3];
  const float* bk = (const float*)d_in[4];
  const float* Wv = (const float*)d_in[5];
  const float* bv = (const float*)d_in[6];
  const float* gamma = (const float*)d_in[7];
  const float* beta  = (const float*)d_in[8];

  float* out1 = (float*)d_out;                       // 4*1024*1024
  float* out2 = out1 + 4L * 1024 * 1024;             // 64*1024 colsums

  short* xb = (short*)d_ws;                          // 4096x1024 bf16
  short* wb = xb + 4L * 1024 * 1024;                 // 3x 1024x1024 bf16
  short* qb = wb + 3L * 1024 * 1024;
  short* kb = qb + 4L * 1024 * 1024;
  short* vtp = kb + 4L * 1024 * 1024;                // V^T frag-major
  float* rvW = (float*)wb;                           // reuse wb after qkv_gemm

  convert_kernel<<<7232, 256, 0, stream>>>(x, Wq, Wk, Wv, xb, wb, out2);
  qkv_gemm<<<dim3(8, 32, 3), 256, 0, stream>>>(xb, wb, bq, bk, bv, qb, kb, vtp);
  attn_kernel<<<512, 256, 0, stream>>>(qb, kb, vtp, x, gamma, beta, out1, rvW);
  colsum_kernel<<<1024, 256, 0, stream>>>(qb, kb, rvW, out2);
}

// Round 7
// 164.372 us; speedup vs baseline: 1.1133x; 1.1133x over previous
//
#include <hip/hip_runtime.h>
#include <hip/hip_bf16.h>
#include <cstdint>
#include <cstddef>

// ---------------------------------------------------------------------------
// MAT_31997506355868 round 16.
// Revert to R14 base (best measured schedule: 3-buf counted-vmcnt, 64-chunks).
// colsum kernel ELIMINATED: fused into attn as sweep 2.  After the flash loop
// computes rv, a K-only second sweep recomputes z with SWAPPED MFMA operands
// (z^T: lane holds j=lm, i=quad*4+r) so the i-reduction for column sums is
// lane-local: per chunk only 2 cross-lane shuffles.  Partials written once
// per (wave,j) into LDS aliased over the dead Vs buffers; cross-wave reduce +
// atomicAdd into out2 (zeroed by convert).  Deletes colsum's launch, ~50 MB
// staging traffic, and the rvW round-trip.
// ---------------------------------------------------------------------------

typedef short short8 __attribute__((ext_vector_type(8)));
typedef short short4v __attribute__((ext_vector_type(4)));
typedef float f32x4 __attribute__((ext_vector_type(4)));

#define MFMA32(a, b, c) __builtin_amdgcn_mfma_f32_16x16x32_bf16(a, b, c, 0, 0, 0)
#define MFMA16x16(a, b, c) __builtin_amdgcn_mfma_f32_16x16x16bf16_1k(a, b, c, 0, 0, 0)
// Q pre-scale: (1/32) * log2(e)  -> scores arrive in log2 domain
#define QSCALE 0.045084220027780106f

__device__ __forceinline__ short f2bf(float f) {
  union { float f; uint32_t u; } x; x.f = f;
  uint32_t u = x.u + 0x7fffu + ((x.u >> 16) & 1u);  // RNE
  return (short)(u >> 16);
}

// pack two fp32 -> two bf16 (truncate) in one v_perm_b32
__device__ __forceinline__ uint32_t pk_bf16_trunc(float lo, float hi) {
  return __builtin_amdgcn_perm(__float_as_uint(hi), __float_as_uint(lo),
                               0x07060302u);
}

// async global->LDS; LDS dest = wave-uniform base + lane*size
#define GLDS16(gp, lp)                                                        \
  __builtin_amdgcn_global_load_lds(                                           \
      (const __attribute__((address_space(1))) void*)(gp),                    \
      (__attribute__((address_space(3))) void*)(lp), 16, 0, 0)

// ---- fp32 -> bf16 convert + zero out2 -------------------------------------
__global__ __launch_bounds__(256) void convert_kernel(
    const float* __restrict__ x, const float* __restrict__ wq,
    const float* __restrict__ wk, const float* __restrict__ wv,
    short* __restrict__ xb, short* __restrict__ wb,
    float* __restrict__ out2) {
  if (blockIdx.x >= 7168) {  // zero out2 (64K floats) for attn sweep-2 atomics
    const int idx = (blockIdx.x - 7168) * 256 + threadIdx.x;
    *(f32x4*)(out2 + (size_t)idx * 4) = (f32x4){0.f, 0.f, 0.f, 0.f};
    return;
  }
  const long XN = 4L * 1024 * 1024, WN = 1024L * 1024;
  long e = (long)(blockIdx.x * blockDim.x + threadIdx.x) * 4;
  const float* src; short* dst;
  if (e < XN)               { src = x  + e;                dst = xb + e; }
  else if (e < XN + WN)     { src = wq + (e - XN);         dst = wb + (e - XN); }
  else if (e < XN + 2 * WN) { src = wk + (e - XN - WN);    dst = wb + (e - XN); }
  else                      { src = wv + (e - XN - 2*WN);  dst = wb + (e - XN); }
  f32x4 v = *(const f32x4*)src;
  short4v o;
  o[0] = f2bf(v[0]); o[1] = f2bf(v[1]); o[2] = f2bf(v[2]); o[3] = f2bf(v[3]);
  *(short4v*)dst = o;
}

// ---- QKV projection: m97 BK=64 + both-sides XOR swizzle.  Q scaled --------
// by (1/32)*log2e so attention uses 2^z.  z==2 (V): writes V^T frag-major.
__global__ __launch_bounds__(256, 3) void qkv_gemm(
    const short* __restrict__ xb, const short* __restrict__ wb,
    const float* __restrict__ bq, const float* __restrict__ bk,
    const float* __restrict__ bv, short* __restrict__ qb,
    short* __restrict__ kb, short* __restrict__ vtp) {
  __shared__ short As[128 * 64];   // 16 KB
  __shared__ short Bs[128 * 64];   // 16 KB
  const int tid = threadIdx.x;
  const int lane = tid & 63;
  const int lm = lane & 15, quad = lane >> 4;
  const int wave = tid >> 6, wy = wave >> 1, wx = wave & 1;
  // flat = bx + 8*by; XCD = flat & 7 (x-fastest round-robin)
  const int f = blockIdx.x + (blockIdx.y << 3);
  const int r8 = f & 7, s = f >> 3;
  const int m0 = (((r8 >> 1) << 3) + (s & 7)) * 128;
  const int n0 = (((r8 & 1) << 2) + (s >> 3)) * 128;
  const int z = blockIdx.z;
  const short* w = wb + (size_t)z * (1024 * 1024);
  const float* bias = (z == 0) ? bq : (z == 1) ? bk : bv;
  const float scl = (z == 0) ? QSCALE : 1.0f;

  // staging: thread t loads row (t>>3)+32q, source chunk (t&7)^(row&7);
  // GLDS dest linear (row-major [128][64]); (row&7) invariant in q.
  const int srow = tid >> 3;
  const int schk = (tid & 7) ^ (srow & 7);
  const short* gA = xb + (size_t)(m0 + srow) * 1024 + schk * 8;
  const short* gB = w  + (size_t)(n0 + srow) * 1024 + schk * 8;
  short* lA = As + tid * 8;
  short* lB = Bs + tid * 8;

  f32x4 acc[4][4];
#pragma unroll
  for (int i = 0; i < 4; i++)
#pragma unroll
    for (int j = 0; j < 4; j++) acc[i][j] = (f32x4){0.f, 0.f, 0.f, 0.f};

  for (int k0 = 0; k0 < 1024; k0 += 64) {
#pragma unroll
    for (int q = 0; q < 4; q++) {
      GLDS16(gA + k0 + q * 32 * 1024, lA + q * 2048);
      GLDS16(gB + k0 + q * 32 * 1024, lB + q * 2048);
    }
    __syncthreads();
#pragma unroll
    for (int ks = 0; ks < 2; ks++) {
      const int ck = (((ks << 2) + quad) ^ (lm & 7)) * 8;  // swizzled chunk
      short8 a[4], b[4];
#pragma unroll
      for (int t = 0; t < 4; t++) {
        a[t] = *(const short8*)(As + (wy * 64 + t * 16 + lm) * 64 + ck);
        b[t] = *(const short8*)(Bs + (wx * 64 + t * 16 + lm) * 64 + ck);
      }
#pragma unroll
      for (int mt = 0; mt < 4; mt++)
#pragma unroll
        for (int nt = 0; nt < 4; nt++)
          acc[mt][nt] = MFMA32(a[mt], b[nt], acc[mt][nt]);
    }
    __syncthreads();
  }
  if (z == 2) {
    // V: write transposed frag-major directly
#pragma unroll
    for (int nt = 0; nt < 4; nt++) {
      const int n = n0 + wx * 64 + nt * 16 + lm;
      const float bn = bias[n];
      const size_t nbase = (size_t)((n >> 4) & 3) * 16384 +
                           (size_t)((((n >> 8) & 3) * 16 + (n & 15)) * 4 +
                                    ((n >> 6) & 3));
#pragma unroll
      for (int mt = 0; mt < 4; mt++) {
#pragma unroll
        for (int r = 0; r < 4; r++) {
          const int m = m0 + wy * 64 + mt * 16 + quad * 4 + r;
          vtp[(size_t)(m >> 6) * 65536 + nbase + (size_t)(m & 63) * 256] =
              f2bf(acc[mt][nt][r] + bn);
        }
      }
    }
  } else {
    short* out = (z == 0) ? qb : kb;
#pragma unroll
    for (int nt = 0; nt < 4; nt++) {
      const int n = n0 + wx * 64 + nt * 16 + lm;
      const float bn = bias[n];
#pragma unroll
      for (int mt = 0; mt < 4; mt++) {
        const int mb = m0 + wy * 64 + mt * 16 + quad * 4;
#pragma unroll
        for (int r = 0; r < 4; r++)
          out[(size_t)(mb + r) * 1024 + n] = f2bf((acc[mt][nt][r] + bn) * scl);
      }
    }
  }
}

// ---- FUSED attention + colsum --------------------------------------------
// Sweep 1 (R14 flash): 2 i-tiles/wave, 64-j chunks, 3-buf K/V, vmcnt(4).
// Sweep 2 (fused colsum): K-only restage (L2-hot), z^T via swapped MFMA
// operands -> i-axis lane-local; col partials -> LDS (aliases Vs) -> atomics.
__global__ __launch_bounds__(256, 2) void attn_kernel(
    const short* __restrict__ qb, const short* __restrict__ kb,
    const short* __restrict__ vtp, const float* __restrict__ x,
    const float* __restrict__ gamma, const float* __restrict__ beta,
    float* __restrict__ out1, float* __restrict__ out2) {
  __shared__ short Ks[3][64 * 64];      // 3 x 8 KB
  __shared__ short Vs[3][4 * 4 * 256];  // 3 x 8 KB (sweep2: aliased as cs)

  const int tid = threadIdx.x;
  const int lane = tid & 63, wave = tid >> 6;
  const int lm = lane & 15, quad = lane >> 4;
  const int bid = blockIdx.x;
  const int h = ((bid >> 6) << 3) + (bid & 7);   // bid ≡ h (mod 8)
  const int bb = (bid >> 3) & 7;
  const short* Qh = qb + (size_t)h * 65536;
  const short* Kh = kb + (size_t)h * 65536;
  const short* Vp = vtp + (size_t)h * 65536;
  const int i0 = bb * 128 + wave * 32;   // tiles at i0 and i0+16

  const short8 qA0 = *(const short8*)(Qh + (size_t)(i0 + lm) * 64 + quad * 8);
  const short8 qA1 = *(const short8*)(Qh + (size_t)(i0 + lm) * 64 + 32 + quad * 8);
  const short8 qB0 = *(const short8*)(Qh + (size_t)(i0 + 16 + lm) * 64 + quad * 8);
  const short8 qB1 = *(const short8*)(Qh + (size_t)(i0 + 16 + lm) * 64 + 32 + quad * 8);

  const int c0 = tid, c1 = tid + 256;
  const short* gK0 = Kh + (size_t)(c0 >> 3) * 64 + ((c0 & 7) ^ ((c0 >> 3) & 7)) * 8;
  const short* gK1 = Kh + (size_t)(c1 >> 3) * 64 + ((c1 & 7) ^ ((c1 >> 3) & 7)) * 8;
  const short* gV0 = Vp + (c0 >> 7) * 16384 + ((c0 >> 5) & 3) * 256 + (c0 & 31) * 8;
  const short* gV1 = Vp + (c1 >> 7) * 16384 + ((c1 >> 5) & 3) * 256 + (c1 & 31) * 8;
  const int lK0 = c0 * 8, lK1 = c1 * 8;

#define ATTN_STAGE(c, buf)                                                    \
  do {                                                                        \
    const int ko_ = ((c) & 15) * 4096, vo_ = ((c) & 15) * 1024;               \
    GLDS16(gK0 + ko_, &Ks[buf][0] + lK0);                                     \
    GLDS16(gK1 + ko_, &Ks[buf][0] + lK1);                                     \
    GLDS16(gV0 + vo_, &Vs[buf][0] + lK0);                                     \
    GLDS16(gV1 + vo_, &Vs[buf][0] + lK1);                                     \
  } while (0)

#define ATTN_STAGE2(c, buf)                                                   \
  do {                                                                        \
    const int ko_ = ((c) & 15) * 4096;                                        \
    GLDS16(gK0 + ko_, &Ks[buf][0] + lK0);                                     \
    GLDS16(gK1 + ko_, &Ks[buf][0] + lK1);                                     \
  } while (0)

  f32x4 accA[4], accB[4];
#pragma unroll
  for (int t = 0; t < 4; t++) {
    accA[t] = (f32x4){0.f, 0.f, 0.f, 0.f};
    accB[t] = (f32x4){0.f, 0.f, 0.f, 0.f};
  }
  float dsA[4] = {0.f, 0.f, 0.f, 0.f};
  float dsB[4] = {0.f, 0.f, 0.f, 0.f};

  const int swz0 = (quad ^ (lm & 7)) * 8;
  const int swz1 = ((quad + 4) ^ (lm & 7)) * 8;

  // ======================= sweep 1: flash attention ========================
  ATTN_STAGE(0, 0);
  ATTN_STAGE(1, 1);

  for (int ch = 0; ch < 16; ch++) {
    const int b = ch % 3, bs = (ch + 2) % 3;
    asm volatile("s_waitcnt vmcnt(4)" ::: "memory");
    __builtin_amdgcn_s_barrier();
    if (ch < 15) ATTN_STAGE(ch + 2, bs);  // ch==14 stages dummy (chunk 0)
    __builtin_amdgcn_s_setprio(1);
#pragma unroll
    for (int jj = 0; jj < 4; jj++) {
      const short* krow = &Ks[b][(jj * 16 + lm) * 64];
      const short8 kf0 = *(const short8*)(krow + swz0);
      const short8 kf1 = *(const short8*)(krow + swz1);
      f32x4 zA = {0.f, 0.f, 0.f, 0.f};
      zA = MFMA32(kf0, qA0, zA);
      zA = MFMA32(kf1, qA1, zA);
      f32x4 zB = {0.f, 0.f, 0.f, 0.f};
      zB = MFMA32(kf0, qB0, zB);
      zB = MFMA32(kf1, qB1, zB);
      float pA[4], pB[4];
#pragma unroll
      for (int r = 0; r < 4; r++) {
        pA[r] = __builtin_amdgcn_exp2f(fmaxf(zA[r], 0.f));  // unnormalized
        dsA[r] += pA[r];
        pB[r] = __builtin_amdgcn_exp2f(fmaxf(zB[r], 0.f));
        dsB[r] += pB[r];
      }
      union { uint32_t u[2]; short4v s; } puA, puB;
      puA.u[0] = pk_bf16_trunc(pA[0], pA[1]);
      puA.u[1] = pk_bf16_trunc(pA[2], pA[3]);
      puB.u[0] = pk_bf16_trunc(pB[0], pB[1]);
      puB.u[1] = pk_bf16_trunc(pB[2], pB[3]);
      const short* vbase = &Vs[b][jj * 256 + lane * 4];
#pragma unroll
      for (int dt = 0; dt < 4; dt++) {
        const short4v vtf = *(const short4v*)(vbase + dt * 1024);
        accA[dt] = MFMA16x16(vtf, puA.s, accA[dt]);
        accB[dt] = MFMA16x16(vtf, puB.s, accB[dt]);
      }
    }
    __builtin_amdgcn_s_setprio(0);
  }
  asm volatile("s_waitcnt vmcnt(0)" ::: "memory");  // drain dummy stage

  float tA = (dsA[0] + dsA[1]) + (dsA[2] + dsA[3]);
  tA += __shfl_xor(tA, 16);
  tA += __shfl_xor(tA, 32);
  float tB = (dsB[0] + dsB[1]) + (dsB[2] + dsB[3]);
  tB += __shfl_xor(tB, 16);
  tB += __shfl_xor(tB, 32);
  const float rvA = 1.f / tA;   // rv for row i0+lm   (uniform across quads)
  const float rvB = 1.f / tB;   // rv for row i0+16+lm

  // ================= sweep 2: fused column sums (colsum) ===================
  // redistribute rv: rvs[r] = rv at row i0(+16) + quad*4 + r  (loop-invariant)
  float rvsA[4], rvsB[4];
#pragma unroll
  for (int r = 0; r < 4; r++) {
    rvsA[r] = __shfl(rvA, quad * 4 + r);
    rvsB[r] = __shfl(rvB, quad * 4 + r);
  }
  __syncthreads();                       // all waves done with Ks/Vs
  float* cs = (float*)&Vs[0][0];         // [4][1024] f32 aliases Vs (16 KB)

  ATTN_STAGE2(0, 0);
  ATTN_STAGE2(1, 1);

  for (int ch = 0; ch < 16; ch++) {
    const int b = ch % 3, bs = (ch + 2) % 3;
    asm volatile("s_waitcnt vmcnt(2)" ::: "memory");
    __builtin_amdgcn_s_barrier();
    if (ch < 15) ATTN_STAGE2(ch + 2, bs);  // ch==14 stages dummy (chunk 0)
    __builtin_amdgcn_s_setprio(1);
#pragma unroll
    for (int jj = 0; jj < 4; jj++) {
      const short* krow = &Ks[b][(jj * 16 + lm) * 64];
      const short8 kf0 = *(const short8*)(krow + swz0);
      const short8 kf1 = *(const short8*)(krow + swz1);
      // SWAPPED operands: z^T -> lane holds (j = ch*64+jj*16+lm,
      // i = i0(+16) + quad*4 + r) -> i-reduction is lane-local.
      f32x4 zA = {0.f, 0.f, 0.f, 0.f};
      zA = MFMA32(qA0, kf0, zA);
      zA = MFMA32(qA1, kf1, zA);
      f32x4 zB = {0.f, 0.f, 0.f, 0.f};
      zB = MFMA32(qB0, kf0, zB);
      zB = MFMA32(qB1, kf1, zB);
      float v = 0.f;
#pragma unroll
      for (int r = 0; r < 4; r++) {
        v += __builtin_amdgcn_exp2f(fmaxf(zA[r], 0.f)) * rvsA[r]
           + __builtin_amdgcn_exp2f(fmaxf(zB[r], 0.f)) * rvsB[r];
      }
      v += __shfl_xor(v, 16);            // sum over quads (i-groups)
      v += __shfl_xor(v, 32);
      if (quad == 0)                     // 16 lanes, consecutive j
        cs[wave * 1024 + ch * 64 + jj * 16 + lm] = v;
    }
    __builtin_amdgcn_s_setprio(0);
  }
  asm volatile("s_waitcnt vmcnt(0)" ::: "memory");
  __syncthreads();
  // cross-wave reduce + merge into out2 (zeroed by convert_kernel)
#pragma unroll
  for (int s = 0; s < 4; s++) {
    const int j = s * 256 + tid;
    const float t4 = (cs[j] + cs[1024 + j]) + (cs[2048 + j] + cs[3072 + j]);
    atomicAdd(out2 + h * 1024 + j, t4);
  }

  // ---- LN epilogue (R4-verified 2-tile): n = lm*64 + dt*16 + quad*4+r -----
  const int mA = h * 64 + bb * 8 + wave * 2;  // tile A row; tile B = mA+1
  const int nb = lm * 64 + quad * 4;
#pragma unroll
  for (int tile = 0; tile < 2; tile++) {
    const int m = mA + tile;
    const f32x4* accT = tile ? accB : accA;
    const float rv = tile ? rvB : rvA;
    const float* xr = x + (size_t)m * 1024;
    float hv[4][4], s1 = 0.f, s2 = 0.f;
#pragma unroll
    for (int dt = 0; dt < 4; dt++) {
      f32x4 xv = *(const f32x4*)(xr + nb + dt * 16);
#pragma unroll
      for (int r = 0; r < 4; r++) {
        const float v = xv[r] + accT[dt][r] * rv;
        hv[dt][r] = v; s1 += v; s2 += v * v;
      }
    }
#pragma unroll
    for (int mk = 1; mk < 64; mk <<= 1) {
      s1 += __shfl_xor(s1, mk);
      s2 += __shfl_xor(s2, mk);
    }
    const float mu = s1 * (1.f / 1024.f);
    const float var = s2 * (1.f / 1024.f) - mu * mu;
    const float rstd = rsqrtf(var + 1e-5f);
    float* orow = out1 + (size_t)m * 1024;
#pragma unroll
    for (int dt = 0; dt < 4; dt++) {
      f32x4 gv = *(const f32x4*)(gamma + nb + dt * 16);
      f32x4 bv2 = *(const f32x4*)(beta + nb + dt * 16);
      f32x4 ov;
#pragma unroll
      for (int r = 0; r < 4; r++)
        ov[r] = (hv[dt][r] - mu) * rstd * gv[r] + bv2[r];
      *(f32x4*)(orow + nb + dt * 16) = ov;
    }
  }
}

extern "C" void kernel_launch(void* const* d_in, const int* in_sizes, int n_in,
                              void* d_out, int out_size, void* d_ws, size_t ws_size,
                              hipStream_t stream) {
  const float* x  = (const float*)d_in[0];
  const float* Wq = (const float*)d_in[1];
  const float* bq = (const float*)d_in[2];
  const float* Wk = (const float*)d_in[3];
  const float* bk = (const float*)d_in[4];
  const float* Wv = (const float*)d_in[5];
  const float* bv = (const float*)d_in[6];
  const float* gamma = (const float*)d_in[7];
  const float* beta  = (const float*)d_in[8];

  float* out1 = (float*)d_out;                       // 4*1024*1024
  float* out2 = out1 + 4L * 1024 * 1024;             // 64*1024 colsums

  short* xb = (short*)d_ws;                          // 4096x1024 bf16
  short* wb = xb + 4L * 1024 * 1024;                 // 3x 1024x1024 bf16
  short* qb = wb + 3L * 1024 * 1024;
  short* kb = qb + 4L * 1024 * 1024;
  short* vtp = kb + 4L * 1024 * 1024;                // V^T frag-major

  convert_kernel<<<7232, 256, 0, stream>>>(x, Wq, Wk, Wv, xb, wb, out2);
  qkv_gemm<<<dim3(8, 32, 3), 256, 0, stream>>>(xb, wb, bq, bk, bv, qb, kb, vtp);
  attn_kernel<<<512, 256, 0, stream>>>(qb, kb, vtp, x, gamma, beta, out1, out2);
}